// Round 1
// baseline (121.366 us; speedup 1.0000x reference)
//
#include <hip/hip_runtime.h>
#include <cstddef>

// Problem constants (from reference)
#define NN   8
#define AA   16368
#define KK   200
#define BB   20
#define PP   4
#define HW2  16384          // 128*128

__device__ __forceinline__ float block_reduce_sum(float v) {
    // wave (64-lane) shuffle reduce, then cross-wave via LDS (256 threads = 4 waves)
    #pragma unroll
    for (int o = 32; o > 0; o >>= 1) v += __shfl_down(v, o, 64);
    __shared__ float s[4];
    const int lane = threadIdx.x & 63;
    const int wid  = threadIdx.x >> 6;
    if (lane == 0) s[wid] = v;
    __syncthreads();
    float r = 0.f;
    if (threadIdx.x == 0) r = s[0] + s[1] + s[2] + s[3];
    return r;   // valid on thread 0 only
}

// BCE(clip(sigmoid(z), eps, 1-eps), y) computed via stable softplus.
// -log(p)   = softplus(-z), -log(1-p) = softplus(z); clip caps both into
// [-log(1-eps), -log(eps)] = [~1e-7, 16.118096].
__device__ __forceinline__ float bce_logit(float z, float y) {
    const float CAP = 16.11809565f;   // -log(1e-7)
    const float LO  = 1.0e-7f;        // -log(1-1e-7)
    float e   = __expf(-fabsf(z));
    float sp  = fmaxf(z, 0.f) + __logf(1.f + e);  // softplus(z)  = -log(1-p)
    float spn = sp - z;                            // softplus(-z) = -log(p)
    float Ln  = fminf(fmaxf(sp,  LO), CAP);
    float Lp  = fminf(fmaxf(spn, LO), CAP);
    return fmaf(y, Lp - Ln, Ln);                   // y*Lp + (1-y)*Ln
}

__device__ __forceinline__ float smooth_l1(float d) {
    float ad = fabsf(d);
    return (ad < 1.f) ? 0.5f * d * d : ad - 0.5f;
}

__global__ void zero_out_kernel(float* out) { out[0] = 0.f; }

// One block per (n,k): z = coef . proto, BCE vs gathered gt mask.
__global__ __launch_bounds__(256) void mask_loss_kernel(
        const float* __restrict__ map_coef,   // [N,A,P]
        const float* __restrict__ proto,      // [N,P,HW2]
        const float* __restrict__ gt_masks,   // [N,B,HW2]
        const int*   __restrict__ pos_idx,    // [N,K]
        const int*   __restrict__ gt_idx,     // [N,K]
        float* __restrict__ out) {
    const int blk = blockIdx.x;          // 0 .. N*K-1
    const int n = blk / KK;
    const int k = blk - n * KK;
    const int a = pos_idx[n * KK + k];
    const int b = gt_idx[n * KK + k];

    const float* cf = map_coef + ((size_t)n * AA + a) * PP;
    const float c0 = cf[0], c1 = cf[1], c2 = cf[2], c3 = cf[3];

    const float4* p0 = (const float4*)(proto + ((size_t)n * PP + 0) * HW2);
    const float4* p1 = (const float4*)(proto + ((size_t)n * PP + 1) * HW2);
    const float4* p2 = (const float4*)(proto + ((size_t)n * PP + 2) * HW2);
    const float4* p3 = (const float4*)(proto + ((size_t)n * PP + 3) * HW2);
    const float4* gm = (const float4*)(gt_masks + ((size_t)n * BB + b) * HW2);

    float acc = 0.f;
    for (int i = threadIdx.x; i < HW2 / 4; i += 256) {
        float4 a0 = p0[i], a1 = p1[i], a2 = p2[i], a3 = p3[i];
        float4 y  = gm[i];
        float z;
        z = fmaf(c0, a0.x, fmaf(c1, a1.x, fmaf(c2, a2.x, c3 * a3.x)));
        acc += bce_logit(z, y.x);
        z = fmaf(c0, a0.y, fmaf(c1, a1.y, fmaf(c2, a2.y, c3 * a3.y)));
        acc += bce_logit(z, y.y);
        z = fmaf(c0, a0.z, fmaf(c1, a1.z, fmaf(c2, a2.z, c3 * a3.z)));
        acc += bce_logit(z, y.z);
        z = fmaf(c0, a0.w, fmaf(c1, a1.w, fmaf(c2, a2.w, c3 * a3.w)));
        acc += bce_logit(z, y.w);
    }

    float tot = block_reduce_sum(acc);
    if (threadIdx.x == 0) {
        // weight: 1/(N*K) for the per-k term, and mean over HW2 pixels
        const float W = 1.0f / ((float)NN * (float)KK * (float)HW2);
        atomicAdd(out, tot * W);
    }
}

// One block per image: classification (pos+neg) and localization losses.
__global__ __launch_bounds__(256) void clsloc_kernel(
        const float* __restrict__ map_class,      // [N,A]
        const float* __restrict__ map_box,        // [N,A,4]
        const float* __restrict__ anchor_center,  // [A,2]
        const float* __restrict__ anchor_hw,      // [A,2]
        const float* __restrict__ gt_boxes,       // [N,B,4]
        const int*   __restrict__ pos_idx,        // [N,K]
        const int*   __restrict__ neg_idx,        // [N,3K]
        const int*   __restrict__ gt_idx,         // [N,K]
        float* __restrict__ out) {
    const int n = blockIdx.x;
    const float EPSF = 1e-7f;
    const float W_CLSPOS = 1.0f / ((float)NN * (float)KK * (float)KK);
    const float W_CLSNEG = 1.0f / ((float)NN * 3.0f * (float)KK * (float)KK);
    const float W_LOC    = 1.0f / ((float)NN * (float)KK);   // ALPHA = 1

    float acc = 0.f;
    // positives: BCE vs 1 plus localization
    for (int k = threadIdx.x; k < KK; k += 256) {
        const int a = pos_idx[n * KK + k];
        const int b = gt_idx[n * KK + k];
        float p = map_class[(size_t)n * AA + a];
        p = fminf(fmaxf(p, EPSF), 1.f - EPSF);
        acc += (-__logf(p)) * W_CLSPOS;

        const float ach = anchor_center[a * 2 + 0];
        const float acw = anchor_center[a * 2 + 1];
        const float ah  = anchor_hw[a * 2 + 0];
        const float aw  = anchor_hw[a * 2 + 1];
        const float* g  = gt_boxes + ((size_t)n * BB + b) * 4;
        const float t0 = (g[0] - ach) / ah;
        const float t1 = (g[1] - acw) / aw;
        const float t2 = __logf(g[2] / ah) * 0.43429448190325176f;  // log10
        const float t3 = __logf(g[3] / aw) * 0.43429448190325176f;
        const float* pr = map_box + ((size_t)n * AA + a) * 4;
        float l = smooth_l1(pr[0] - t0) + smooth_l1(pr[1] - t1)
                + smooth_l1(pr[2] - t2) + smooth_l1(pr[3] - t3);
        acc += l * W_LOC;
    }
    // negatives: BCE vs 0
    for (int j = threadIdx.x; j < 3 * KK; j += 256) {
        const int a = neg_idx[n * 3 * KK + j];
        float p = map_class[(size_t)n * AA + a];
        p = fminf(fmaxf(p, EPSF), 1.f - EPSF);
        acc += (-__logf(1.f - p)) * W_CLSNEG;
    }

    float tot = block_reduce_sum(acc);
    if (threadIdx.x == 0) atomicAdd(out, tot);
}

extern "C" void kernel_launch(void* const* d_in, const int* in_sizes, int n_in,
                              void* d_out, int out_size, void* d_ws, size_t ws_size,
                              hipStream_t stream) {
    const float* map_class     = (const float*)d_in[0];
    const float* map_box       = (const float*)d_in[1];
    const float* map_coef      = (const float*)d_in[2];
    const float* proto         = (const float*)d_in[3];
    const float* anchor_center = (const float*)d_in[4];
    const float* anchor_hw     = (const float*)d_in[5];
    const float* gt_boxes      = (const float*)d_in[6];
    const float* gt_masks      = (const float*)d_in[7];
    const int*   pos_idx       = (const int*)d_in[8];
    const int*   neg_idx       = (const int*)d_in[9];
    const int*   gt_idx        = (const int*)d_in[10];
    float* out = (float*)d_out;

    zero_out_kernel<<<1, 1, 0, stream>>>(out);
    clsloc_kernel<<<NN, 256, 0, stream>>>(map_class, map_box, anchor_center,
                                          anchor_hw, gt_boxes, pos_idx, neg_idx,
                                          gt_idx, out);
    mask_loss_kernel<<<NN * KK, 256, 0, stream>>>(map_coef, proto, gt_masks,
                                                  pos_idx, gt_idx, out);
}